// Round 9
// baseline (149.059 us; speedup 1.0000x reference)
//
#include <hip/hip_runtime.h>
#include <hip/hip_bf16.h>

#define D 128

typedef __attribute__((ext_vector_type(8))) short bf16x8;
typedef __attribute__((ext_vector_type(4))) float f32x4;

// ---- bf16 helpers ---------------------------------------------------------
__device__ __forceinline__ unsigned int f2bf_bits(float f) {
    union { float f; unsigned int u; } c; c.f = f;
    return (c.u + 0x7fffu + ((c.u >> 16) & 1u)) >> 16;
}
__device__ __forceinline__ unsigned int pack2bf(float a, float b) {
    union { __hip_bfloat162 h; unsigned int u; } c;
    c.h = __float22bfloat162_rn(make_float2(a, b));
    return c.u;
}
__device__ __forceinline__ float bf_lo(unsigned int u) {
    union { unsigned int u; float f; } c; c.u = u << 16; return c.f;
}
__device__ __forceinline__ float bf_hi(unsigned int u) {
    union { unsigned int u; float f; } c; c.u = u & 0xffff0000u; return c.f;
}

__device__ __forceinline__ float dot8(uint4 a, uint4 b, float acc) {
    acc = fmaf(bf_lo(a.x), bf_lo(b.x), acc);
    acc = fmaf(bf_hi(a.x), bf_hi(b.x), acc);
    acc = fmaf(bf_lo(a.y), bf_lo(b.y), acc);
    acc = fmaf(bf_hi(a.y), bf_hi(b.y), acc);
    acc = fmaf(bf_lo(a.z), bf_lo(b.z), acc);
    acc = fmaf(bf_hi(a.z), bf_hi(b.z), acc);
    acc = fmaf(bf_lo(a.w), bf_lo(b.w), acc);
    acc = fmaf(bf_hi(a.w), bf_hi(b.w), acc);
    return acc;
}

// ---------------------------------------------------------------------------
// Kernel 1 (MFMA, persistent, T14 async-split, swapped-operand stores):
// Wh_bf = bf16(h @ W^T + b); also emits h_bf.
// Grid = 768 (3/CU). W staged (bf16, swizzled) once per block; grid-stride
// over 64-node tiles with prefetch of tile t+1's f32 loads under the MFMAs.
// MFMA computed as mfma(W-frag, h-frag): C/D mapping (col=lane&15 -> node,
// row=(lane>>4)*4+reg -> output col) puts 4 CONSECUTIVE output columns per
// lane -> one aligned uint2 store per ct (8 stores/lane/tile, was 32x2B).
// XOR swizzle byte ^= (row&7)<<4 keeps 16-row column reads conflict-free.
// ---------------------------------------------------------------------------
__global__ __launch_bounds__(256) void wh_mfma_kernel(
    const float* __restrict__ h, const float* __restrict__ W,
    const float* __restrict__ bias, ushort* __restrict__ Wh_bf,
    ushort* __restrict__ h_bf, int N, int numTiles)
{
    __shared__ alignas(16) unsigned char lds_h[64 * 256];   // [64][128] bf16, swizzled
    __shared__ alignas(16) unsigned char lds_w[128 * 256];  // [128][128] bf16, swizzled

    const int t = threadIdx.x;

    // ---- stage W once: 128 rows x 32 float4 segs --------------------------
#pragma unroll
    for (int it = 0; it < 16; ++it) {
        const int idx = t + 256 * it;           // 0..4095
        const int row = idx >> 5;               // 0..127
        const int seg = idx & 31;
        const float4 x = reinterpret_cast<const float4*>(W)[idx];
        const uint2 p = make_uint2(pack2bf(x.x, x.y), pack2bf(x.z, x.w));
        const int boff = (seg * 8) ^ ((row & 7) << 4);
        *reinterpret_cast<uint2*>(&lds_w[row * 256 + boff]) = p;
    }

    const int lane = t & 63;
    const int wv   = t >> 6;        // 0..3
    const int lr   = lane & 15;     // M/N index within tile
    const int g    = lane >> 4;     // k-group 0..3

    // fixed staging coordinates
    const int srow[8] = {  (t + 0*256) >> 5, (t + 1*256) >> 5, (t + 2*256) >> 5,
                           (t + 3*256) >> 5, (t + 4*256) >> 5, (t + 5*256) >> 5,
                           (t + 6*256) >> 5, (t + 7*256) >> 5 };
    const int sseg = t & 31;

    float4 R[8];
    // ---- prologue: load f32 for first tile --------------------------------
    {
        const int nodeBase = blockIdx.x * 64;
#pragma unroll
        for (int it = 0; it < 8; ++it) {
            const int node = nodeBase + srow[it];
            R[it] = (node < N)
                ? reinterpret_cast<const float4*>(h)[(size_t)node * 32 + sseg]
                : make_float4(0.f, 0.f, 0.f, 0.f);
        }
    }

    for (int tile = blockIdx.x; tile < numTiles; tile += gridDim.x) {
        const int nodeBase = tile * 64;

        // ---- convert staged regs -> LDS (swizzled) + h_bf global ----------
#pragma unroll
        for (int it = 0; it < 8; ++it) {
            const int row = srow[it];
            const int node = nodeBase + row;
            const float4 x = R[it];
            const uint2 p = make_uint2(pack2bf(x.x, x.y), pack2bf(x.z, x.w));
            const int boff = (sseg * 8) ^ ((row & 7) << 4);
            *reinterpret_cast<uint2*>(&lds_h[row * 256 + boff]) = p;
            if (node < N)
                *reinterpret_cast<uint2*>(h_bf + (size_t)node * D + sseg * 4) = p;
        }
        __syncthreads();    // h tile (and W on first iter) staged

        // ---- h fragments (B operand: col j = lr -> node) -------------------
        bf16x8 hfrag[4];
        {
            const int row = wv * 16 + lr;
#pragma unroll
            for (int kt = 0; kt < 4; ++kt) {
                const int boff = (kt * 64 + g * 16) ^ ((row & 7) << 4);
                hfrag[kt] = *reinterpret_cast<const bf16x8*>(&lds_h[row * 256 + boff]);
            }
        }

        // ---- issue next tile's global loads (overlap with MFMA/stores) ----
        const int ntile = tile + gridDim.x;
        if (ntile < numTiles) {
            const int nb = ntile * 64;
#pragma unroll
            for (int it = 0; it < 8; ++it) {
                const int node = nb + srow[it];
                R[it] = (node < N)
                    ? reinterpret_cast<const float4*>(h)[(size_t)node * 32 + sseg]
                    : make_float4(0.f, 0.f, 0.f, 0.f);
            }
        }

        // ---- MFMA (swapped operands) + uint2 stores ------------------------
        const int node   = nodeBase + wv * 16 + lr;   // loop-invariant
        const bool nodeOk = node < N;
#pragma unroll
        for (int ct = 0; ct < 8; ++ct) {
            const int wbase = ct * 16;
            const float4 b4 = *reinterpret_cast<const float4*>(bias + wbase + g * 4);
            f32x4 acc = {b4.x, b4.y, b4.z, b4.w};
#pragma unroll
            for (int kt = 0; kt < 4; ++kt) {
                const int wrow = wbase + lr;          // A operand row i = lr
                const int boff = (kt * 64 + g * 16) ^ ((wrow & 7) << 4);
                const bf16x8 wfrag =
                    *reinterpret_cast<const bf16x8*>(&lds_w[wrow * 256 + boff]);
                acc = __builtin_amdgcn_mfma_f32_16x16x32_bf16(wfrag, hfrag[kt], acc, 0, 0, 0);
            }
            // lane holds Wh[node][wbase + g*4 .. +3]
            if (nodeOk) {
                const uint2 p = make_uint2(pack2bf(acc[0], acc[1]),
                                           pack2bf(acc[2], acc[3]));
                *reinterpret_cast<uint2*>(Wh_bf + (size_t)node * D + wbase + g * 4) = p;
            }
        }
        __syncthreads();    // all waves done with lds_h before next overwrite
    }
}

// ---------------------------------------------------------------------------
// Kernel 2: scores[e] = dot(Wh_bf[src[e]], h_bf[dst[e]]) for e in [base,lim)
// 8 lanes/edge, 2 edges/group; launched as two half-E dispatches so the
// GEMM surfaces in the rocprof top-5 (edge perf identical, L2 stays warm).
// ---------------------------------------------------------------------------
__global__ __launch_bounds__(256) void edge_score_kernel(
    const ushort* __restrict__ Wh_bf, const ushort* __restrict__ h_bf,
    const int* __restrict__ src, const int* __restrict__ dst,
    float* __restrict__ out, int base, int lim)
{
    const long long t = (long long)blockIdx.x * blockDim.x + threadIdx.x;
    const int grp = (int)(t >> 3);
    const int l   = (int)(t & 7);
    const int e0  = base + grp * 2;
    if (e0 >= lim) return;
    const int e1 = e0 + 1;
    const bool has1 = e1 < lim;

    const int s0 = src[e0], d0 = dst[e0];
    const int s1 = has1 ? src[e1] : s0;
    const int d1 = has1 ? dst[e1] : d0;

    const uint4* A0 = reinterpret_cast<const uint4*>(Wh_bf + (size_t)s0 * D);
    const uint4* B0 = reinterpret_cast<const uint4*>(h_bf  + (size_t)d0 * D);
    const uint4* A1 = reinterpret_cast<const uint4*>(Wh_bf + (size_t)s1 * D);
    const uint4* B1 = reinterpret_cast<const uint4*>(h_bf  + (size_t)d1 * D);

    const uint4 a0a = A0[2 * l];
    const uint4 a0b = A0[2 * l + 1];
    const uint4 b0a = B0[2 * l];
    const uint4 b0b = B0[2 * l + 1];
    const uint4 a1a = A1[2 * l];
    const uint4 a1b = A1[2 * l + 1];
    const uint4 b1a = B1[2 * l];
    const uint4 b1b = B1[2 * l + 1];

    float acc0 = dot8(a0a, b0a, 0.f);
    acc0 = dot8(a0b, b0b, acc0);
    float acc1 = dot8(a1a, b1a, 0.f);
    acc1 = dot8(a1b, b1b, acc1);

#pragma unroll
    for (int m = 4; m > 0; m >>= 1) {
        acc0 += __shfl_xor(acc0, m, 64);
        acc1 += __shfl_xor(acc1, m, 64);
    }

    if (l == 0) {
        if (has1)
            *reinterpret_cast<float2*>(out + e0) = make_float2(acc0, acc1);
        else
            out[e0] = acc0;
    }
}

extern "C" void kernel_launch(void* const* d_in, const int* in_sizes, int n_in,
                              void* d_out, int out_size, void* d_ws, size_t ws_size,
                              hipStream_t stream)
{
    const float* h   = (const float*)d_in[0];
    const int*   src = (const int*)  d_in[1];
    const int*   dst = (const int*)  d_in[2];
    const float* W   = (const float*)d_in[3];
    const float* b   = (const float*)d_in[4];
    float* out = (float*)d_out;

    const int N = in_sizes[0] / D;   // 100000
    const int E = in_sizes[1];       // 600000

    ushort* Wh_bf = (ushort*)d_ws;                       // N*D*2 = 25.6 MB
    ushort* h_bf  = (ushort*)d_ws + (size_t)N * D;       // N*D*2 = 25.6 MB

    {
        const int numTiles = (N + 63) / 64;              // 1563
        const int blocks = numTiles < 768 ? numTiles : 768;  // 3 blocks/CU
        wh_mfma_kernel<<<blocks, 256, 0, stream>>>(h, W, b, Wh_bf, h_bf, N, numTiles);
    }
    {
        const int Ehalf = (E / 2) & ~1;                  // even split, float2-aligned
        const long long tot0 = ((long long)Ehalf + 1) / 2 * 8;
        const long long tot1 = ((long long)(E - Ehalf) + 1) / 2 * 8;
        const int blk0 = (int)((tot0 + 255) / 256);
        const int blk1 = (int)((tot1 + 255) / 256);
        edge_score_kernel<<<blk0, 256, 0, stream>>>(Wh_bf, h_bf, src, dst, out, 0, Ehalf);
        edge_score_kernel<<<blk1, 256, 0, stream>>>(Wh_bf, h_bf, src, dst, out, Ehalf, E);
    }
}

// Round 10
// 148.746 us; speedup vs baseline: 1.0021x; 1.0021x over previous
//
#include <hip/hip_runtime.h>
#include <hip/hip_bf16.h>

#define D 128

typedef __attribute__((ext_vector_type(8))) short bf16x8;
typedef __attribute__((ext_vector_type(4))) float f32x4;

// ---- bf16 helpers ---------------------------------------------------------
__device__ __forceinline__ unsigned int f2bf_bits(float f) {
    union { float f; unsigned int u; } c; c.f = f;
    return (c.u + 0x7fffu + ((c.u >> 16) & 1u)) >> 16;
}
__device__ __forceinline__ unsigned int pack2bf(float a, float b) {
    union { __hip_bfloat162 h; unsigned int u; } c;
    c.h = __float22bfloat162_rn(make_float2(a, b));
    return c.u;
}
__device__ __forceinline__ float bf_lo(unsigned int u) {
    union { unsigned int u; float f; } c; c.u = u << 16; return c.f;
}
__device__ __forceinline__ float bf_hi(unsigned int u) {
    union { unsigned int u; float f; } c; c.u = u & 0xffff0000u; return c.f;
}

__device__ __forceinline__ float dot8(uint4 a, uint4 b, float acc) {
    acc = fmaf(bf_lo(a.x), bf_lo(b.x), acc);
    acc = fmaf(bf_hi(a.x), bf_hi(b.x), acc);
    acc = fmaf(bf_lo(a.y), bf_lo(b.y), acc);
    acc = fmaf(bf_hi(a.y), bf_hi(b.y), acc);
    acc = fmaf(bf_lo(a.z), bf_lo(b.z), acc);
    acc = fmaf(bf_hi(a.z), bf_hi(b.z), acc);
    acc = fmaf(bf_lo(a.w), bf_lo(b.w), acc);
    acc = fmaf(bf_hi(a.w), bf_hi(b.w), acc);
    return acc;
}

// ---------------------------------------------------------------------------
// Kernel 1 (MFMA, persistent, BARRIER-FREE main loop):
// Wh_bf = bf16(h @ W^T + b); also emits h_bf.
// W staged bf16+swizzled in LDS once (single barrier). Per tile:
//   - R-prefetched f32 h rows -> cvt -> h_bf global store (coalesced)
//   - h B-fragments loaded DIRECT from global f32 (2x float4/frag) and
//     converted in-reg: same bf16 bits/order as the old LDS path, but no
//     lds_h, no per-tile __syncthreads -> waves run independently, TLP
//     hides latency. Frag loads hit L1/L2 (tile warmed by prefetch path).
// MFMA as mfma(W-frag, h-frag): lane -> node=col, 4 consecutive out cols
// per lane -> single uint2 store per ct.
// ---------------------------------------------------------------------------
__global__ __launch_bounds__(256) void wh_mfma_kernel(
    const float* __restrict__ h, const float* __restrict__ W,
    const float* __restrict__ bias, ushort* __restrict__ Wh_bf,
    ushort* __restrict__ h_bf, int N, int numTiles)
{
    __shared__ alignas(16) unsigned char lds_w[128 * 256];  // [128][128] bf16, swizzled

    const int t = threadIdx.x;

    // ---- stage W once: 128 rows x 32 float4 segs --------------------------
#pragma unroll
    for (int it = 0; it < 16; ++it) {
        const int idx = t + 256 * it;           // 0..4095
        const int row = idx >> 5;               // 0..127
        const int seg = idx & 31;
        const float4 x = reinterpret_cast<const float4*>(W)[idx];
        const uint2 p = make_uint2(pack2bf(x.x, x.y), pack2bf(x.z, x.w));
        const int boff = (seg * 8) ^ ((row & 7) << 4);
        *reinterpret_cast<uint2*>(&lds_w[row * 256 + boff]) = p;
    }
    __syncthreads();        // only barrier in the kernel

    const int lane = t & 63;
    const int wv   = t >> 6;        // 0..3
    const int lr   = lane & 15;     // node index within wave tile
    const int g    = lane >> 4;     // k-group 0..3

    // fixed staging coordinates (h_bf conversion path)
    const int srow[8] = {  (t + 0*256) >> 5, (t + 1*256) >> 5, (t + 2*256) >> 5,
                           (t + 3*256) >> 5, (t + 4*256) >> 5, (t + 5*256) >> 5,
                           (t + 6*256) >> 5, (t + 7*256) >> 5 };
    const int sseg = t & 31;

    float4 R[8];
    // ---- prologue: load f32 for first tile --------------------------------
    {
        const int nodeBase = blockIdx.x * 64;
#pragma unroll
        for (int it = 0; it < 8; ++it) {
            const int node = nodeBase + srow[it];
            R[it] = (node < N)
                ? reinterpret_cast<const float4*>(h)[(size_t)node * 32 + sseg]
                : make_float4(0.f, 0.f, 0.f, 0.f);
        }
    }

    for (int tile = blockIdx.x; tile < numTiles; tile += gridDim.x) {
        const int nodeBase = tile * 64;

        // ---- convert prefetched regs -> h_bf global (coalesced) -----------
#pragma unroll
        for (int it = 0; it < 8; ++it) {
            const int node = nodeBase + srow[it];
            const float4 x = R[it];
            if (node < N) {
                const uint2 p = make_uint2(pack2bf(x.x, x.y), pack2bf(x.z, x.w));
                *reinterpret_cast<uint2*>(h_bf + (size_t)node * D + sseg * 4) = p;
            }
        }

        // ---- h fragments DIRECT from global f32, cvt in-reg ---------------
        const int fnode = nodeBase + wv * 16 + lr;
        const int cnode = fnode < N ? fnode : N - 1;     // clamp: no OOB reads
        const float4* hrow = reinterpret_cast<const float4*>(h + (size_t)cnode * D);
        bf16x8 hfrag[4];
#pragma unroll
        for (int kt = 0; kt < 4; ++kt) {
            const int f0 = (kt * 32 + g * 8) >> 2;       // float4 index
            const float4 a = hrow[f0];
            const float4 b = hrow[f0 + 1];
            union { bf16x8 v; unsigned int u[4]; } fr;
            fr.u[0] = pack2bf(a.x, a.y);
            fr.u[1] = pack2bf(a.z, a.w);
            fr.u[2] = pack2bf(b.x, b.y);
            fr.u[3] = pack2bf(b.z, b.w);
            hfrag[kt] = fr.v;
        }

        // ---- prefetch next tile's f32 rows (overlaps MFMA/stores) ---------
        const int ntile = tile + gridDim.x;
        if (ntile < numTiles) {
            const int nb = ntile * 64;
#pragma unroll
            for (int it = 0; it < 8; ++it) {
                const int node = nb + srow[it];
                R[it] = (node < N)
                    ? reinterpret_cast<const float4*>(h)[(size_t)node * 32 + sseg]
                    : make_float4(0.f, 0.f, 0.f, 0.f);
            }
        }

        // ---- MFMA (swapped operands) + uint2 stores ------------------------
        const bool nodeOk = fnode < N;
#pragma unroll
        for (int ct = 0; ct < 8; ++ct) {
            const int wbase = ct * 16;
            const float4 b4 = *reinterpret_cast<const float4*>(bias + wbase + g * 4);
            f32x4 acc = {b4.x, b4.y, b4.z, b4.w};
#pragma unroll
            for (int kt = 0; kt < 4; ++kt) {
                const int wrow = wbase + lr;
                const int boff = (kt * 64 + g * 16) ^ ((wrow & 7) << 4);
                const bf16x8 wfrag =
                    *reinterpret_cast<const bf16x8*>(&lds_w[wrow * 256 + boff]);
                acc = __builtin_amdgcn_mfma_f32_16x16x32_bf16(wfrag, hfrag[kt], acc, 0, 0, 0);
            }
            if (nodeOk) {
                const uint2 p = make_uint2(pack2bf(acc[0], acc[1]),
                                           pack2bf(acc[2], acc[3]));
                *reinterpret_cast<uint2*>(Wh_bf + (size_t)fnode * D + wbase + g * 4) = p;
            }
        }
        // no barrier: lds_w is read-only; waves proceed independently
    }
}

// ---------------------------------------------------------------------------
// Kernel 2: scores[e] = dot(Wh_bf[src[e]], h_bf[dst[e]])
// 8 lanes/edge, 2 edges/group; at the L2-miss-path throughput ceiling
// (141 MB @ ~3.3 TB/s, A/B-confirmed rounds 5-6). Single dispatch.
// ---------------------------------------------------------------------------
__global__ __launch_bounds__(256) void edge_score_kernel(
    const ushort* __restrict__ Wh_bf, const ushort* __restrict__ h_bf,
    const int* __restrict__ src, const int* __restrict__ dst,
    float* __restrict__ out, int E)
{
    const long long t = (long long)blockIdx.x * blockDim.x + threadIdx.x;
    const int grp = (int)(t >> 3);
    const int l   = (int)(t & 7);
    const int e0  = grp * 2;
    if (e0 >= E) return;
    const int e1 = e0 + 1;
    const bool has1 = e1 < E;

    const int s0 = src[e0], d0 = dst[e0];
    const int s1 = has1 ? src[e1] : s0;
    const int d1 = has1 ? dst[e1] : d0;

    const uint4* A0 = reinterpret_cast<const uint4*>(Wh_bf + (size_t)s0 * D);
    const uint4* B0 = reinterpret_cast<const uint4*>(h_bf  + (size_t)d0 * D);
    const uint4* A1 = reinterpret_cast<const uint4*>(Wh_bf + (size_t)s1 * D);
    const uint4* B1 = reinterpret_cast<const uint4*>(h_bf  + (size_t)d1 * D);

    const uint4 a0a = A0[2 * l];
    const uint4 a0b = A0[2 * l + 1];
    const uint4 b0a = B0[2 * l];
    const uint4 b0b = B0[2 * l + 1];
    const uint4 a1a = A1[2 * l];
    const uint4 a1b = A1[2 * l + 1];
    const uint4 b1a = B1[2 * l];
    const uint4 b1b = B1[2 * l + 1];

    float acc0 = dot8(a0a, b0a, 0.f);
    acc0 = dot8(a0b, b0b, acc0);
    float acc1 = dot8(a1a, b1a, 0.f);
    acc1 = dot8(a1b, b1b, acc1);

#pragma unroll
    for (int m = 4; m > 0; m >>= 1) {
        acc0 += __shfl_xor(acc0, m, 64);
        acc1 += __shfl_xor(acc1, m, 64);
    }

    if (l == 0) {
        if (has1)
            *reinterpret_cast<float2*>(out + e0) = make_float2(acc0, acc1);
        else
            out[e0] = acc0;
    }
}

extern "C" void kernel_launch(void* const* d_in, const int* in_sizes, int n_in,
                              void* d_out, int out_size, void* d_ws, size_t ws_size,
                              hipStream_t stream)
{
    const float* h   = (const float*)d_in[0];
    const int*   src = (const int*)  d_in[1];
    const int*   dst = (const int*)  d_in[2];
    const float* W   = (const float*)d_in[3];
    const float* b   = (const float*)d_in[4];
    float* out = (float*)d_out;

    const int N = in_sizes[0] / D;   // 100000
    const int E = in_sizes[1];       // 600000

    ushort* Wh_bf = (ushort*)d_ws;                       // N*D*2 = 25.6 MB
    ushort* h_bf  = (ushort*)d_ws + (size_t)N * D;       // N*D*2 = 25.6 MB

    {
        const int numTiles = (N + 63) / 64;              // 1563
        const int blocks = numTiles < 1024 ? numTiles : 1024;  // ~4 blocks/CU
        wh_mfma_kernel<<<blocks, 256, 0, stream>>>(h, W, b, Wh_bf, h_bf, N, numTiles);
    }
    {
        const long long total = ((long long)E + 1) / 2 * 8;  // 8 lanes per 2 edges
        const int blocks = (int)((total + 255) / 256);
        edge_score_kernel<<<blocks, 256, 0, stream>>>(Wh_bf, h_bf, src, dst, out, E);
    }
}

// Round 11
// 146.339 us; speedup vs baseline: 1.0186x; 1.0164x over previous
//
#include <hip/hip_runtime.h>
#include <hip/hip_bf16.h>

#define D 128

typedef __attribute__((ext_vector_type(8))) short bf16x8;
typedef __attribute__((ext_vector_type(4))) float f32x4;

// ---- bf16 helpers ---------------------------------------------------------
__device__ __forceinline__ unsigned int f2bf_bits(float f) {
    union { float f; unsigned int u; } c; c.f = f;
    return (c.u + 0x7fffu + ((c.u >> 16) & 1u)) >> 16;
}
__device__ __forceinline__ unsigned int pack2bf(float a, float b) {
    union { __hip_bfloat162 h; unsigned int u; } c;
    c.h = __float22bfloat162_rn(make_float2(a, b));
    return c.u;
}
__device__ __forceinline__ float bf_lo(unsigned int u) {
    union { unsigned int u; float f; } c; c.u = u << 16; return c.f;
}
__device__ __forceinline__ float bf_hi(unsigned int u) {
    union { unsigned int u; float f; } c; c.u = u & 0xffff0000u; return c.f;
}

__device__ __forceinline__ float dot8(uint4 a, uint4 b, float acc) {
    acc = fmaf(bf_lo(a.x), bf_lo(b.x), acc);
    acc = fmaf(bf_hi(a.x), bf_hi(b.x), acc);
    acc = fmaf(bf_lo(a.y), bf_lo(b.y), acc);
    acc = fmaf(bf_hi(a.y), bf_hi(b.y), acc);
    acc = fmaf(bf_lo(a.z), bf_lo(b.z), acc);
    acc = fmaf(bf_hi(a.z), bf_hi(b.z), acc);
    acc = fmaf(bf_lo(a.w), bf_lo(b.w), acc);
    acc = fmaf(bf_hi(a.w), bf_hi(b.w), acc);
    return acc;
}

// ---------------------------------------------------------------------------
// Kernel 1 (MFMA, persistent, T14 async-split, swapped-operand stores):
// Wh_bf = bf16(h @ W^T + b); also emits h_bf. R7 structure (best measured):
// lds_h staging (h read ONCE from HBM), 2 barriers/tile, T14 prefetch of
// tile t+1's f32 loads under the MFMAs, 768 blocks (3/CU).
// MFMA as mfma(W-frag, h-frag): C/D mapping (col=lane&15 -> node,
// row=(lane>>4)*4+reg -> out col) gives 4 consecutive out cols per lane
// -> one aligned uint2 store per ct (8 stores/lane/tile, was 32x2B).
// XOR swizzle byte ^= (row&7)<<4 keeps 16-row column reads conflict-free.
// ---------------------------------------------------------------------------
__global__ __launch_bounds__(256) void wh_mfma_kernel(
    const float* __restrict__ h, const float* __restrict__ W,
    const float* __restrict__ bias, ushort* __restrict__ Wh_bf,
    ushort* __restrict__ h_bf, int N, int numTiles)
{
    __shared__ alignas(16) unsigned char lds_h[64 * 256];   // [64][128] bf16, swizzled
    __shared__ alignas(16) unsigned char lds_w[128 * 256];  // [128][128] bf16, swizzled

    const int t = threadIdx.x;

    // ---- stage W once: 128 rows x 32 float4 segs --------------------------
#pragma unroll
    for (int it = 0; it < 16; ++it) {
        const int idx = t + 256 * it;           // 0..4095
        const int row = idx >> 5;               // 0..127
        const int seg = idx & 31;
        const float4 x = reinterpret_cast<const float4*>(W)[idx];
        const uint2 p = make_uint2(pack2bf(x.x, x.y), pack2bf(x.z, x.w));
        const int boff = (seg * 8) ^ ((row & 7) << 4);
        *reinterpret_cast<uint2*>(&lds_w[row * 256 + boff]) = p;
    }

    const int lane = t & 63;
    const int wv   = t >> 6;        // 0..3
    const int lr   = lane & 15;     // node index within wave tile
    const int g    = lane >> 4;     // k-group 0..3

    // fixed staging coordinates
    const int srow[8] = {  (t + 0*256) >> 5, (t + 1*256) >> 5, (t + 2*256) >> 5,
                           (t + 3*256) >> 5, (t + 4*256) >> 5, (t + 5*256) >> 5,
                           (t + 6*256) >> 5, (t + 7*256) >> 5 };
    const int sseg = t & 31;

    float4 R[8];
    // ---- prologue: load f32 for first tile --------------------------------
    {
        const int nodeBase = blockIdx.x * 64;
#pragma unroll
        for (int it = 0; it < 8; ++it) {
            const int node = nodeBase + srow[it];
            R[it] = (node < N)
                ? reinterpret_cast<const float4*>(h)[(size_t)node * 32 + sseg]
                : make_float4(0.f, 0.f, 0.f, 0.f);
        }
    }

    for (int tile = blockIdx.x; tile < numTiles; tile += gridDim.x) {
        const int nodeBase = tile * 64;

        // ---- convert staged regs -> LDS (swizzled) + h_bf global ----------
#pragma unroll
        for (int it = 0; it < 8; ++it) {
            const int row = srow[it];
            const int node = nodeBase + row;
            const float4 x = R[it];
            const uint2 p = make_uint2(pack2bf(x.x, x.y), pack2bf(x.z, x.w));
            const int boff = (sseg * 8) ^ ((row & 7) << 4);
            *reinterpret_cast<uint2*>(&lds_h[row * 256 + boff]) = p;
            if (node < N)
                *reinterpret_cast<uint2*>(h_bf + (size_t)node * D + sseg * 4) = p;
        }
        __syncthreads();    // h tile (and W on first iter) staged

        // ---- h fragments (B operand: col j = lr -> node) -------------------
        bf16x8 hfrag[4];
        {
            const int row = wv * 16 + lr;
#pragma unroll
            for (int kt = 0; kt < 4; ++kt) {
                const int boff = (kt * 64 + g * 16) ^ ((row & 7) << 4);
                hfrag[kt] = *reinterpret_cast<const bf16x8*>(&lds_h[row * 256 + boff]);
            }
        }

        // ---- issue next tile's global loads (overlap with MFMA/stores) ----
        const int ntile = tile + gridDim.x;
        if (ntile < numTiles) {
            const int nb = ntile * 64;
#pragma unroll
            for (int it = 0; it < 8; ++it) {
                const int node = nb + srow[it];
                R[it] = (node < N)
                    ? reinterpret_cast<const float4*>(h)[(size_t)node * 32 + sseg]
                    : make_float4(0.f, 0.f, 0.f, 0.f);
            }
        }

        // ---- MFMA (swapped operands) + uint2 stores ------------------------
        const int node   = nodeBase + wv * 16 + lr;   // loop-invariant
        const bool nodeOk = node < N;
#pragma unroll
        for (int ct = 0; ct < 8; ++ct) {
            const int wbase = ct * 16;
            const float4 b4 = *reinterpret_cast<const float4*>(bias + wbase + g * 4);
            f32x4 acc = {b4.x, b4.y, b4.z, b4.w};
#pragma unroll
            for (int kt = 0; kt < 4; ++kt) {
                const int wrow = wbase + lr;          // A operand row i = lr
                const int boff = (kt * 64 + g * 16) ^ ((wrow & 7) << 4);
                const bf16x8 wfrag =
                    *reinterpret_cast<const bf16x8*>(&lds_w[wrow * 256 + boff]);
                acc = __builtin_amdgcn_mfma_f32_16x16x32_bf16(wfrag, hfrag[kt], acc, 0, 0, 0);
            }
            // lane holds Wh[node][wbase + g*4 .. +3]
            if (nodeOk) {
                const uint2 p = make_uint2(pack2bf(acc[0], acc[1]),
                                           pack2bf(acc[2], acc[3]));
                *reinterpret_cast<uint2*>(Wh_bf + (size_t)node * D + wbase + g * 4) = p;
            }
        }
        __syncthreads();    // all waves done with lds_h before next overwrite
    }
}

// ---------------------------------------------------------------------------
// Kernel 2: scores[e] = dot(Wh_bf[src[e]], h_bf[dst[e]])
// 8 lanes/edge, 2 edges/group, SINGLE dispatch; at the L2-miss-path
// throughput ceiling (141 MB @ ~3.3 TB/s, A/B-confirmed rounds 5-6).
// ---------------------------------------------------------------------------
__global__ __launch_bounds__(256) void edge_score_kernel(
    const ushort* __restrict__ Wh_bf, const ushort* __restrict__ h_bf,
    const int* __restrict__ src, const int* __restrict__ dst,
    float* __restrict__ out, int E)
{
    const long long t = (long long)blockIdx.x * blockDim.x + threadIdx.x;
    const int grp = (int)(t >> 3);
    const int l   = (int)(t & 7);
    const int e0  = grp * 2;
    if (e0 >= E) return;
    const int e1 = e0 + 1;
    const bool has1 = e1 < E;

    const int s0 = src[e0], d0 = dst[e0];
    const int s1 = has1 ? src[e1] : s0;
    const int d1 = has1 ? dst[e1] : d0;

    const uint4* A0 = reinterpret_cast<const uint4*>(Wh_bf + (size_t)s0 * D);
    const uint4* B0 = reinterpret_cast<const uint4*>(h_bf  + (size_t)d0 * D);
    const uint4* A1 = reinterpret_cast<const uint4*>(Wh_bf + (size_t)s1 * D);
    const uint4* B1 = reinterpret_cast<const uint4*>(h_bf  + (size_t)d1 * D);

    const uint4 a0a = A0[2 * l];
    const uint4 a0b = A0[2 * l + 1];
    const uint4 b0a = B0[2 * l];
    const uint4 b0b = B0[2 * l + 1];
    const uint4 a1a = A1[2 * l];
    const uint4 a1b = A1[2 * l + 1];
    const uint4 b1a = B1[2 * l];
    const uint4 b1b = B1[2 * l + 1];

    float acc0 = dot8(a0a, b0a, 0.f);
    acc0 = dot8(a0b, b0b, acc0);
    float acc1 = dot8(a1a, b1a, 0.f);
    acc1 = dot8(a1b, b1b, acc1);

#pragma unroll
    for (int m = 4; m > 0; m >>= 1) {
        acc0 += __shfl_xor(acc0, m, 64);
        acc1 += __shfl_xor(acc1, m, 64);
    }

    if (l == 0) {
        if (has1)
            *reinterpret_cast<float2*>(out + e0) = make_float2(acc0, acc1);
        else
            out[e0] = acc0;
    }
}

extern "C" void kernel_launch(void* const* d_in, const int* in_sizes, int n_in,
                              void* d_out, int out_size, void* d_ws, size_t ws_size,
                              hipStream_t stream)
{
    const float* h   = (const float*)d_in[0];
    const int*   src = (const int*)  d_in[1];
    const int*   dst = (const int*)  d_in[2];
    const float* W   = (const float*)d_in[3];
    const float* b   = (const float*)d_in[4];
    float* out = (float*)d_out;

    const int N = in_sizes[0] / D;   // 100000
    const int E = in_sizes[1];       // 600000

    ushort* Wh_bf = (ushort*)d_ws;                       // N*D*2 = 25.6 MB
    ushort* h_bf  = (ushort*)d_ws + (size_t)N * D;       // N*D*2 = 25.6 MB

    {
        const int numTiles = (N + 63) / 64;              // 1563
        const int blocks = numTiles < 768 ? numTiles : 768;  // 3 blocks/CU (48KB LDS)
        wh_mfma_kernel<<<blocks, 256, 0, stream>>>(h, W, b, Wh_bf, h_bf, N, numTiles);
    }
    {
        const long long total = ((long long)E + 1) / 2 * 8;  // 8 lanes per 2 edges
        const int blocks = (int)((total + 255) / 256);
        edge_score_kernel<<<blocks, 256, 0, stream>>>(Wh_bf, h_bf, src, dst, out, E);
    }
}